// Round 9
// baseline (249.953 us; speedup 1.0000x reference)
//
#include <hip/hip_runtime.h>
#include <stdint.h>

// ---------------------------------------------------------------------------
// NIVR: coord-MLP over 512x512 grid.
//   pre_kernel (1024 blocks): blocks 0..511: time branch inline + Txp/Ty
//     posenc tables (tvec folded into Txp); blocks 512..1023: W2f -> bf16
//     W2s (32x32x16 A-operand frags).
//   main: h1 = relu(Txp[x]+Ty[y]); layer2 via MFMA bf16 32x32x16 (swapped
//     operands => acc holds h2^T); fused layer3 epilogue. Out [3][N].
//
// R18 vs R17: K-loop was DS-BW bound in every prior variant: each wave
// re-read ALL of A (per CU/step: 32 ds_read_b128 = 256-384 cyc) vs only
// 128 SIMD-cyc of matrix work => MfmaUtil pinned ~35%. Balance needs
// nN = 4 B-frags per A-read (DS W*mA*8 = matrix W*mA*nN*2).
// R18: BM=128, 8 waves as 2M x 4N: wave = 2 A-frags (64-pix half) x
// 4 B-frags (128-col slice) = 8 MFMA/step; DS 16 reads/CU/step ~= matrix.
// B read 2x/block but 2048 blocks => 2 GB L2 (58us floor, same as before).
// acc 2x4xf32x16 = 128 AGPR; full depth-1 prefetch areg[2][2]+breg[2][4]
// = 124 VGPR + 128 AGPR = 252 (R16-proven clean). Whole-A 128KB filled
// once (R16-verified layout, 2.1M conflicts), 1 barrier, stagger kofs=4w,
// setprio. Serial fill ~12k cyc/block accepted (next target).
// ---------------------------------------------------------------------------

typedef short bf16x8 __attribute__((ext_vector_type(8)));
typedef float f32x16 __attribute__((ext_vector_type(16)));

#define PI_F 3.14159265358979323846f
#define SIDE 512
#define NPIX (SIDE * SIDE)

__device__ __forceinline__ unsigned short f2bf(float f) {
  unsigned int u = __float_as_uint(f);
  u += 0x7fffu + ((u >> 16) & 1u);
  return (unsigned short)(u >> 16);
}

// ---------------------------------------------------------------------------
// pre: 1024 blocks x 512 threads (R17-verified).
//   b in [0,512)    : time branch (redundant per block) -> tvec;
//                     Txp[b][k] = tvec[k] + sum_l enc[l] W1f[l][k]
//                     Ty [b][k] =           sum_l enc[l] W1f[20+l][k]
//   b in [512,1024) : W2f -> bf16 W2s, 32x32x16 A-operand frags:
//                     W2s[kstep*8192 + nt32*512 + (hi*32+lo)*8 + j]
//                       = bf16(W2f[kstep*16 + hi*8 + j][nt32*32 + lo])
// ---------------------------------------------------------------------------
__global__ void pre_kernel(const float* __restrict__ W1p, const float* __restrict__ b1p,
                           const float* __restrict__ W2p, const float* __restrict__ b2p,
                           const float* __restrict__ W1f, const float* __restrict__ b1f,
                           const float* __restrict__ W2f, const int* __restrict__ idx,
                           float* __restrict__ Txp, float* __restrict__ Ty,
                           unsigned short* __restrict__ W2s) {
  const int b = blockIdx.x;
  const int t = threadIdx.x;

  if (b >= 512) {
    const int k = b - 512, n = t;
    const int kstep = k >> 4, hi = (k >> 3) & 1, j = k & 7;
    const int nt32 = n >> 5, lo = n & 31;
    W2s[kstep * 8192 + nt32 * 512 + (hi * 32 + lo) * 8 + j] = f2bf(W2f[k * 512 + n]);
    return;
  }

  __shared__ float enc[20];
  __shared__ float r_s[32];
  __shared__ float h_s[256];
  __shared__ float phi_s[128];

  if (t < 10) {
    float u = (float)b / 512.0f;
    float ang = u * ldexpf(PI_F, t);
    enc[t] = sinf(ang);
    enc[10 + t] = cosf(ang);
  }
  if (t >= 32 && t < 48) {
    const int l = t - 32;
    float tt = (float)idx[0] / 300.0f;
    float ang = tt * ldexpf(PI_F, l);
    r_s[l] = sinf(ang);
    r_s[16 + l] = cosf(ang);
  }
  __syncthreads();
  if (t < 256) {
    float a = b1p[t];
#pragma unroll
    for (int i = 0; i < 32; ++i) a += r_s[i] * W1p[i * 256 + t];
    h_s[t] = fmaxf(a, 0.f);
  }
  __syncthreads();
  if (t < 128) {
    float a = b2p[t];
    for (int i = 0; i < 256; ++i) a += h_s[i] * W2p[i * 128 + t];
    phi_s[t] = a;
  }
  __syncthreads();
  {
    float tv = b1f[t];
    for (int p = 0; p < 128; ++p) tv += phi_s[p] * W1f[(40 + p) * 512 + t];
    float ax = tv, ay = 0.f;
#pragma unroll
    for (int l = 0; l < 20; ++l) {
      ax += enc[l] * W1f[l * 512 + t];
      ay += enc[l] * W1f[(20 + l) * 512 + t];
    }
    Txp[b * 512 + t] = ax;
    Ty[b * 512 + t] = ay;
  }
}

// ---------------------------------------------------------------------------
// Main fused kernel. Block = 512 thr (8 waves), BM=128 (16x8 pixel patch),
// BN=512, K=512 in 32 steps of 16 k. Whole A tile (128KB) resident in LDS.
// Wave w: mh = w>>2 owns pixels [mh*64,+64) (A-frags mh*2, mh*2+1);
//         nq = w&3  owns n-cols  [nq*128,+128) (B-frags nq*4 .. +3).
// Per step per wave: 2 A ds_read_b128 + 4 B 16B loads (all prefetched one
// step ahead), 8 MFMA 32x32x16 (nN=4 per A-read => DS/matrix balanced).
// A storage (shorts): elem (p,k) at (k>>4)*2048 + (p>>5)*512
//                      + ((k>>3)&1)*256 + (p&31)*8 + (k&7)   [R16-verified]
// acc[mi][nn] reg r: h2[pix = (mh*2+mi)*32 + (lane&31)]
//                   [n = nq*128 + nn*32 + (r&3) + 8*(r>>2) + 4*(lane>>5)]
// ---------------------------------------------------------------------------
__global__ __launch_bounds__(512, 2) void main_kernel(
    const float* __restrict__ Txp, const float* __restrict__ Ty,
    const unsigned short* __restrict__ W2s, const float* __restrict__ b2f,
    const float* __restrict__ W3f, const float* __restrict__ b3f,
    float* __restrict__ out) {
  __shared__ __attribute__((aligned(16))) unsigned short Ab[32 * 2048];  // 128KB
  __shared__ float part[4][128][3];                                      // 6KB

  const int t = threadIdx.x;
  const int w = t >> 6;            // wave id 0..7
  const int lane = t & 63;
  const int lo = lane & 31;
  const int hi = lane >> 5;
  const int mh = w >> 2;           // M half (0,1)
  const int nq = w & 3;            // N quarter
  const int x0 = blockIdx.x * 16, y0 = blockIdx.y * 8;

  // per-wave K-phase offset over the 32 steps (SGPR)
  const int kofs = __builtin_amdgcn_readfirstlane((w * 4) & 31);

  // B: frag (kstep, nn) at W2s + kstep*8192 + (nq*4+nn)*512 + lane*8
  const unsigned short* bptr = W2s + (nq * 4) * 512 + lane * 8;

  // ---- B pipeline init (issued before fill: long-latency loads drain
  // during the fill). breg[ks&1] used at loop pos ks. ----
  bf16x8 breg[2][4];
#pragma unroll
  for (int nn = 0; nn < 4; ++nn)
    breg[0][nn] = *(const bf16x8*)(bptr + kofs * 8192 + nn * 512);

  // ---- A fill (whole tile, once; R16-verified geometry): thread
  // (p = t>>2, s = t&3) covers pixel p (0..127), k = 16*g + s*4..+3. ----
  {
    const int p = t >> 2, s = t & 3;
    const int xi = x0 + (p >> 3), yi = y0 + (p & 7);
    const float* txp = Txp + xi * 512 + s * 4;
    const float* typ = Ty + yi * 512 + s * 4;
    const int abase = (p >> 5) * 512 + (s >> 1) * 256 + (p & 31) * 8 + (s & 1) * 4;
#pragma unroll
    for (int g = 0; g < 32; ++g) {
      float4 a = *(const float4*)(txp + g * 16);
      float4 b = *(const float4*)(typ + g * 16);
      float v0 = fmaxf(a.x + b.x, 0.f);
      float v1 = fmaxf(a.y + b.y, 0.f);
      float v2 = fmaxf(a.z + b.z, 0.f);
      float v3 = fmaxf(a.w + b.w, 0.f);
      uint2 pk;
      asm("v_cvt_pk_bf16_f32 %0, %1, %2" : "=v"(pk.x) : "v"(v0), "v"(v1));
      asm("v_cvt_pk_bf16_f32 %0, %1, %2" : "=v"(pk.y) : "v"(v2), "v"(v3));
      *(uint2*)&Ab[g * 2048 + abase] = pk;
    }
  }

  f32x16 acc[2][4];
#pragma unroll
  for (int mi = 0; mi < 2; ++mi)
#pragma unroll
    for (int nn = 0; nn < 4; ++nn)
#pragma unroll
      for (int r = 0; r < 16; ++r) acc[mi][nn][r] = 0.f;

  __syncthreads();  // publishes A; the only barrier before the epilogue

  // ---- A pipeline init: depth 1. areg[ks&1] used at loop pos ks. ----
  bf16x8 areg[2][2];
#pragma unroll
  for (int mi = 0; mi < 2; ++mi)
    areg[0][mi] =
        *(const bf16x8*)&Ab[kofs * 2048 + (mh * 2 + mi) * 512 + lane * 8];

  // ---- K-loop: 32 steps, fully unrolled, no barriers, wave-staggered.
  // All loads for step ks+1 issued before this step's MFMAs. ----
#pragma unroll
  for (int ks = 0; ks < 32; ++ks) {
    const int kkl = (ks + kofs) & 31;
    if (ks < 31) {
      const int knl = (kkl + 1) & 31;
#pragma unroll
      for (int nn = 0; nn < 4; ++nn)
        breg[(ks + 1) & 1][nn] =
            *(const bf16x8*)(bptr + knl * 8192 + nn * 512);
      const unsigned short* arow = &Ab[knl * 2048 + lane * 8];
#pragma unroll
      for (int mi = 0; mi < 2; ++mi)
        areg[(ks + 1) & 1][mi] = *(const bf16x8*)&arow[(mh * 2 + mi) * 512];
    }
    __builtin_amdgcn_s_setprio(1);
#pragma unroll
    for (int nn = 0; nn < 4; ++nn) {
      acc[0][nn] = __builtin_amdgcn_mfma_f32_32x32x16_bf16(
          breg[ks & 1][nn], areg[ks & 1][0], acc[0][nn], 0, 0, 0);
      acc[1][nn] = __builtin_amdgcn_mfma_f32_32x32x16_bf16(
          breg[ks & 1][nn], areg[ks & 1][1], acc[1][nn], 0, 0, 0);
    }
    __builtin_amdgcn_s_setprio(0);
  }

  // ---- epilogue: h2 = relu(acc + b2f); rgb partial = h2 @ W3f.
  // Lane: pixels (mh*2+mi)*32+lo, n-cols nq*128 + nn*32 + rq*8 + hi*4 + e.
  // shfl_xor(32) combines hi-halves; part[nq] planes summed at the end. ----
  {
    float p3[2][3];
#pragma unroll
    for (int mi = 0; mi < 2; ++mi) {
      p3[mi][0] = 0.f; p3[mi][1] = 0.f; p3[mi][2] = 0.f;
    }
#pragma unroll
    for (int nn = 0; nn < 4; ++nn) {
#pragma unroll
      for (int rq = 0; rq < 4; ++rq) {
        const int n0 = nq * 128 + nn * 32 + rq * 8 + hi * 4;
        float4 bv = *(const float4*)&b2f[n0];
        float4 u0 = *(const float4*)&W3f[n0 * 3 + 0];
        float4 u1 = *(const float4*)&W3f[n0 * 3 + 4];
        float4 u2 = *(const float4*)&W3f[n0 * 3 + 8];
#pragma unroll
        for (int mi = 0; mi < 2; ++mi) {
          float h0 = fmaxf(acc[mi][nn][rq * 4 + 0] + bv.x, 0.f);
          float h1 = fmaxf(acc[mi][nn][rq * 4 + 1] + bv.y, 0.f);
          float h2 = fmaxf(acc[mi][nn][rq * 4 + 2] + bv.z, 0.f);
          float h3 = fmaxf(acc[mi][nn][rq * 4 + 3] + bv.w, 0.f);
          p3[mi][0] += h0 * u0.x + h1 * u0.w + h2 * u1.z + h3 * u2.y;
          p3[mi][1] += h0 * u0.y + h1 * u1.x + h2 * u1.w + h3 * u2.z;
          p3[mi][2] += h0 * u0.z + h1 * u1.y + h2 * u2.x + h3 * u2.w;
        }
      }
    }
#pragma unroll
    for (int mi = 0; mi < 2; ++mi)
#pragma unroll
      for (int cc = 0; cc < 3; ++cc)
        p3[mi][cc] += __shfl_xor(p3[mi][cc], 32, 64);
    if (hi == 0) {
#pragma unroll
      for (int mi = 0; mi < 2; ++mi)
#pragma unroll
        for (int cc = 0; cc < 3; ++cc)
          part[nq][(mh * 2 + mi) * 32 + lo][cc] = p3[mi][cc];
    }
  }
  __syncthreads();
  if (t < 384) {
    const int c = t >> 7, pp = t & 127;
    float sum = b3f[c] + part[0][pp][c] + part[1][pp][c] +
                part[2][pp][c] + part[3][pp][c];
    out[c * NPIX + (x0 + (pp >> 3)) * 512 + (y0 + (pp & 7))] = sum;
  }
}

// ---------------------------------------------------------------------------
// Inputs: 0 coords (unused), 1 W1p, 2 b1p, 3 W2p, 4 b2p, 5 W1f, 6 b1f,
//         7 W2f, 8 b2f, 9 W3f, 10 b3f, 11 idx
// ---------------------------------------------------------------------------
extern "C" void kernel_launch(void* const* d_in, const int* in_sizes, int n_in,
                              void* d_out, int out_size, void* d_ws, size_t ws_size,
                              hipStream_t stream) {
  const float* W1p = (const float*)d_in[1];
  const float* b1p = (const float*)d_in[2];
  const float* W2p = (const float*)d_in[3];
  const float* b2p = (const float*)d_in[4];
  const float* W1f = (const float*)d_in[5];
  const float* b1f = (const float*)d_in[6];
  const float* W2f = (const float*)d_in[7];
  const float* b2f = (const float*)d_in[8];
  const float* W3f = (const float*)d_in[9];
  const float* b3f = (const float*)d_in[10];
  const int* idx = (const int*)d_in[11];
  float* out = (float*)d_out;

  char* ws = (char*)d_ws;
  float* Txp = (float*)ws;                                   // 1 MB
  float* Ty = (float*)(ws + (1u << 20));                     // 1 MB
  unsigned short* W2s = (unsigned short*)(ws + (2u << 20));  // 512 KB

  hipLaunchKernelGGL(pre_kernel, dim3(1024), dim3(512), 0, stream,
                     W1p, b1p, W2p, b2p, W1f, b1f, W2f, idx, Txp, Ty, W2s);
  hipLaunchKernelGGL(main_kernel, dim3(32, 64), dim3(512), 0, stream,
                     Txp, Ty, W2s, b2f, W3f, b3f, out);
}

// Round 10
// 246.863 us; speedup vs baseline: 1.0125x; 1.0125x over previous
//
#include <hip/hip_runtime.h>
#include <stdint.h>

// ---------------------------------------------------------------------------
// NIVR: coord-MLP over 512x512 grid.
//   pre_kernel (1024 blocks): blocks 0..511: time branch inline + Txp/Ty
//     posenc tables (tvec folded into Txp); blocks 512..1023: W2f -> bf16
//     W2s (32x32x16 A-operand frags).
//   main: h1 = relu(Txp[x]+Ty[y]); layer2 via MFMA bf16 32x32x16 (swapped
//     operands => acc holds h2^T); fused layer3 epilogue. Out [3][N].
//
// R19: constraint-space sweep closed the design space:
//   A-DS/CU = 268MB*(512/N_wave)/256 (98k cyc @64); B-L2/CU =
//   0.5MB*(262144/M_wave)/256 (146k @64, 73k @128); acc = M_wave*N_wave/64.
//   acc<=64 (4 w/SIMD) => M*N<=4096; max(A-DS,B-L2) minimized at (64,64).
//   => R12/R17 geometry optimal; floor 61us; all M_wave=128 variants need
//   2 w/SIMD or spill (R14/15/16/18 all measured worse). Game = overlap.
// R19 = R17 repaired to a clean 110-reg budget:
//   - at-use A reads (TLP covers ~120cyc DS latency at 4 w/SIMD; R12-proven)
//   - freed 16 regs -> B depth-2 (breg[3][2]: ~512cyc cover > L2 ~300)
//   - b128 fill (8 iters) into bank-skewed layout (step pitch 1032 shorts,
//     derived write pattern 2 words/bank = free; was 6.3M conflicts)
//   - stagger kofs=4w + setprio kept. LDS 72KB x2 = 144KB, 2 blocks/CU.
// Live: 64 acc + 24 breg + 8 a + ~14 misc ~ 110 <= 128 cap (512,4).
// ---------------------------------------------------------------------------

typedef short bf16x8 __attribute__((ext_vector_type(8)));
typedef float f32x16 __attribute__((ext_vector_type(16)));

#define PI_F 3.14159265358979323846f
#define SIDE 512
#define NPIX (SIDE * SIDE)
#define AP 1032  // A step pitch in shorts (1024 + 8 skew: banks rotate 4/step)

__device__ __forceinline__ unsigned short f2bf(float f) {
  unsigned int u = __float_as_uint(f);
  u += 0x7fffu + ((u >> 16) & 1u);
  return (unsigned short)(u >> 16);
}

// ---------------------------------------------------------------------------
// pre: 1024 blocks x 512 threads (R17/R18-verified).
//   b in [0,512)    : time branch (redundant per block) -> tvec;
//                     Txp[b][k] = tvec[k] + sum_l enc[l] W1f[l][k]
//                     Ty [b][k] =           sum_l enc[l] W1f[20+l][k]
//   b in [512,1024) : W2f -> bf16 W2s, 32x32x16 A-operand frags:
//                     W2s[kstep*8192 + nt32*512 + (hi*32+lo)*8 + j]
//                       = bf16(W2f[kstep*16 + hi*8 + j][nt32*32 + lo])
// ---------------------------------------------------------------------------
__global__ void pre_kernel(const float* __restrict__ W1p, const float* __restrict__ b1p,
                           const float* __restrict__ W2p, const float* __restrict__ b2p,
                           const float* __restrict__ W1f, const float* __restrict__ b1f,
                           const float* __restrict__ W2f, const int* __restrict__ idx,
                           float* __restrict__ Txp, float* __restrict__ Ty,
                           unsigned short* __restrict__ W2s) {
  const int b = blockIdx.x;
  const int t = threadIdx.x;

  if (b >= 512) {
    const int k = b - 512, n = t;
    const int kstep = k >> 4, hi = (k >> 3) & 1, j = k & 7;
    const int nt32 = n >> 5, lo = n & 31;
    W2s[kstep * 8192 + nt32 * 512 + (hi * 32 + lo) * 8 + j] = f2bf(W2f[k * 512 + n]);
    return;
  }

  __shared__ float enc[20];
  __shared__ float r_s[32];
  __shared__ float h_s[256];
  __shared__ float phi_s[128];

  if (t < 10) {
    float u = (float)b / 512.0f;
    float ang = u * ldexpf(PI_F, t);
    enc[t] = sinf(ang);
    enc[10 + t] = cosf(ang);
  }
  if (t >= 32 && t < 48) {
    const int l = t - 32;
    float tt = (float)idx[0] / 300.0f;
    float ang = tt * ldexpf(PI_F, l);
    r_s[l] = sinf(ang);
    r_s[16 + l] = cosf(ang);
  }
  __syncthreads();
  if (t < 256) {
    float a = b1p[t];
#pragma unroll
    for (int i = 0; i < 32; ++i) a += r_s[i] * W1p[i * 256 + t];
    h_s[t] = fmaxf(a, 0.f);
  }
  __syncthreads();
  if (t < 128) {
    float a = b2p[t];
    for (int i = 0; i < 256; ++i) a += h_s[i] * W2p[i * 128 + t];
    phi_s[t] = a;
  }
  __syncthreads();
  {
    float tv = b1f[t];
    for (int p = 0; p < 128; ++p) tv += phi_s[p] * W1f[(40 + p) * 512 + t];
    float ax = tv, ay = 0.f;
#pragma unroll
    for (int l = 0; l < 20; ++l) {
      ax += enc[l] * W1f[l * 512 + t];
      ay += enc[l] * W1f[(20 + l) * 512 + t];
    }
    Txp[b * 512 + t] = ax;
    Ty[b * 512 + t] = ay;
  }
}

// ---------------------------------------------------------------------------
// Main fused kernel. Block = 512 thr (8 waves), BM=64 (8x8 patch), BN=512,
// K=512 in 32 steps of 16 k. Whole A tile (66KB skewed) resident in LDS.
// Wave w owns n-cols [w*64,+64) -- all 8 col-slices distinct => B read ONCE
// per block (512KB; 4096 blocks => 2GB L2 = the 61us structural floor).
// Per step per wave: 2 A ds_read_b128 (at use) + 2 B 16B loads (depth-2
// prefetch, breg[3][2]) + 4 MFMA 32x32x16.
// A storage (shorts): elem (p,k) at (k>>4)*AP + (p>>5)*512
//                      + ((k>>3)&1)*256 + (p&31)*8 + (k&7)
// acc[mi][nn] reg r: h2[pix = mi*32 + (lane&31)]
//                   [n = w*64 + nn*32 + (r&3) + 8*(r>>2) + 4*(lane>>5)]
// ---------------------------------------------------------------------------
__global__ __launch_bounds__(512, 4) void main_kernel(
    const float* __restrict__ Txp, const float* __restrict__ Ty,
    const unsigned short* __restrict__ W2s, const float* __restrict__ b2f,
    const float* __restrict__ W3f, const float* __restrict__ b3f,
    float* __restrict__ out) {
  __shared__ __attribute__((aligned(16))) unsigned short Ab[32 * AP];  // 66KB
  __shared__ float part[8][64][3];                                     // 6KB

  const int t = threadIdx.x;
  const int w = t >> 6;            // wave id 0..7 (owns n-slice [w*64,+64))
  const int lane = t & 63;
  const int lo = lane & 31;
  const int hi = lane >> 5;
  const int x0 = blockIdx.x * 8, y0 = blockIdx.y * 8;

  // per-wave K-phase offset over the 32 steps (SGPR)
  const int kofs = __builtin_amdgcn_readfirstlane((w * 4) & 31);

  // B: frag (kstep, nn) at W2s + kstep*8192 + (w*2+nn)*512 + lane*8
  const unsigned short* bptr = W2s + (w * 2) * 512 + lane * 8;

  // ---- B pipeline init: depth 2 (3 buffers), issued BEFORE the fill so
  // their L2/HBM latency drains under the fill. breg[ks%3] used at pos ks.
  bf16x8 breg[3][2];
#pragma unroll
  for (int nn = 0; nn < 2; ++nn) {
    breg[0][nn] = *(const bf16x8*)(bptr + kofs * 8192 + nn * 512);
    breg[1][nn] = *(const bf16x8*)(bptr + (((kofs + 1) & 31) * 8192) + nn * 512);
  }

  // ---- A fill (whole tile, once): thread (p = t>>3, s = t&7) covers pixel
  // p (0..63), 8-k block kb = g*8 + s (g = 0..7): one ds_write_b128 each.
  // Write addr (shorts): (kb>>1)*AP + (p>>5)*512 + (kb&1)*256 + (p&31)*8.
  // Skewed pitch => derived write pattern ~2 words/bank (free).
  {
    const int p = t >> 3, s = t & 7;
    const int xi = x0 + (p >> 3), yi = y0 + (p & 7);
    const float* txp = Txp + xi * 512;
    const float* typ = Ty + yi * 512;
    const int pbase = (p >> 5) * 512 + (p & 31) * 8;
#pragma unroll
    for (int g = 0; g < 8; ++g) {
      const int kb = g * 8 + s;
      float4 a0 = *(const float4*)(txp + kb * 8);
      float4 a1 = *(const float4*)(txp + kb * 8 + 4);
      float4 b0 = *(const float4*)(typ + kb * 8);
      float4 b1 = *(const float4*)(typ + kb * 8 + 4);
      float v0 = fmaxf(a0.x + b0.x, 0.f), v1 = fmaxf(a0.y + b0.y, 0.f);
      float v2 = fmaxf(a0.z + b0.z, 0.f), v3 = fmaxf(a0.w + b0.w, 0.f);
      float v4 = fmaxf(a1.x + b1.x, 0.f), v5 = fmaxf(a1.y + b1.y, 0.f);
      float v6 = fmaxf(a1.z + b1.z, 0.f), v7 = fmaxf(a1.w + b1.w, 0.f);
      uint4 pk;
      asm("v_cvt_pk_bf16_f32 %0, %1, %2" : "=v"(pk.x) : "v"(v0), "v"(v1));
      asm("v_cvt_pk_bf16_f32 %0, %1, %2" : "=v"(pk.y) : "v"(v2), "v"(v3));
      asm("v_cvt_pk_bf16_f32 %0, %1, %2" : "=v"(pk.z) : "v"(v4), "v"(v5));
      asm("v_cvt_pk_bf16_f32 %0, %1, %2" : "=v"(pk.w) : "v"(v6), "v"(v7));
      *(uint4*)&Ab[(kb >> 1) * AP + (kb & 1) * 256 + pbase] = pk;
    }
  }

  f32x16 acc[2][2];
#pragma unroll
  for (int mi = 0; mi < 2; ++mi)
#pragma unroll
    for (int nn = 0; nn < 2; ++nn)
#pragma unroll
      for (int r = 0; r < 16; ++r) acc[mi][nn][r] = 0.f;

  __syncthreads();  // publishes A; the only barrier before the epilogue

  // ---- K-loop: 32 steps, fully unrolled, no barriers, wave-staggered.
  // B prefetch depth 2 (covers ~2 step-walls >= L2 latency); A at use
  // (TLP: 3 sibling waves/SIMD cover the ~120cyc DS latency). ----
#pragma unroll
  for (int ks = 0; ks < 32; ++ks) {
    const int kkl = (ks + kofs) & 31;
    if (ks + 2 < 32) {
      const int kn2 = (kkl + 2) & 31;
#pragma unroll
      for (int nn = 0; nn < 2; ++nn)
        breg[(ks + 2) % 3][nn] =
            *(const bf16x8*)(bptr + kn2 * 8192 + nn * 512);
    }
    // A-frags at use: 2 ds_read_b128 from the skewed tile
    bf16x8 a0 = *(const bf16x8*)&Ab[kkl * AP + lane * 8];
    bf16x8 a1 = *(const bf16x8*)&Ab[kkl * AP + 512 + lane * 8];
    __builtin_amdgcn_s_setprio(1);
    acc[0][0] = __builtin_amdgcn_mfma_f32_32x32x16_bf16(
        breg[ks % 3][0], a0, acc[0][0], 0, 0, 0);
    acc[1][0] = __builtin_amdgcn_mfma_f32_32x32x16_bf16(
        breg[ks % 3][0], a1, acc[1][0], 0, 0, 0);
    acc[0][1] = __builtin_amdgcn_mfma_f32_32x32x16_bf16(
        breg[ks % 3][1], a0, acc[0][1], 0, 0, 0);
    acc[1][1] = __builtin_amdgcn_mfma_f32_32x32x16_bf16(
        breg[ks % 3][1], a1, acc[1][1], 0, 0, 0);
    __builtin_amdgcn_s_setprio(0);
  }

  // ---- epilogue: h2 = relu(acc + b2f); rgb partial = h2 @ W3f.
  // Lane: pixels mi*32+lo, n-cols w*64 + nn*32 + rq*8 + hi*4 + e.
  // shfl_xor(32) combines hi-halves. ----
  {
    float p3[2][3];
#pragma unroll
    for (int mi = 0; mi < 2; ++mi) {
      p3[mi][0] = 0.f; p3[mi][1] = 0.f; p3[mi][2] = 0.f;
    }
#pragma unroll
    for (int nn = 0; nn < 2; ++nn) {
#pragma unroll
      for (int rq = 0; rq < 4; ++rq) {
        const int n0 = w * 64 + nn * 32 + rq * 8 + hi * 4;
        float4 bv = *(const float4*)&b2f[n0];
        float4 u0 = *(const float4*)&W3f[n0 * 3 + 0];
        float4 u1 = *(const float4*)&W3f[n0 * 3 + 4];
        float4 u2 = *(const float4*)&W3f[n0 * 3 + 8];
#pragma unroll
        for (int mi = 0; mi < 2; ++mi) {
          float h0 = fmaxf(acc[mi][nn][rq * 4 + 0] + bv.x, 0.f);
          float h1 = fmaxf(acc[mi][nn][rq * 4 + 1] + bv.y, 0.f);
          float h2 = fmaxf(acc[mi][nn][rq * 4 + 2] + bv.z, 0.f);
          float h3 = fmaxf(acc[mi][nn][rq * 4 + 3] + bv.w, 0.f);
          p3[mi][0] += h0 * u0.x + h1 * u0.w + h2 * u1.z + h3 * u2.y;
          p3[mi][1] += h0 * u0.y + h1 * u1.x + h2 * u1.w + h3 * u2.z;
          p3[mi][2] += h0 * u0.z + h1 * u1.y + h2 * u2.x + h3 * u2.w;
        }
      }
    }
#pragma unroll
    for (int mi = 0; mi < 2; ++mi)
#pragma unroll
      for (int cc = 0; cc < 3; ++cc)
        p3[mi][cc] += __shfl_xor(p3[mi][cc], 32, 64);
    if (hi == 0) {
#pragma unroll
      for (int mi = 0; mi < 2; ++mi)
#pragma unroll
        for (int cc = 0; cc < 3; ++cc)
          part[w][mi * 32 + lo][cc] = p3[mi][cc];
    }
  }
  __syncthreads();
  if (t < 192) {
    const int c = t >> 6, pp = t & 63;
    float sum = b3f[c];
#pragma unroll
    for (int ww = 0; ww < 8; ++ww) sum += part[ww][pp][c];
    out[c * NPIX + (x0 + (pp >> 3)) * 512 + (y0 + (pp & 7))] = sum;
  }
}

// ---------------------------------------------------------------------------
// Inputs: 0 coords (unused), 1 W1p, 2 b1p, 3 W2p, 4 b2p, 5 W1f, 6 b1f,
//         7 W2f, 8 b2f, 9 W3f, 10 b3f, 11 idx
// ---------------------------------------------------------------------------
extern "C" void kernel_launch(void* const* d_in, const int* in_sizes, int n_in,
                              void* d_out, int out_size, void* d_ws, size_t ws_size,
                              hipStream_t stream) {
  const float* W1p = (const float*)d_in[1];
  const float* b1p = (const float*)d_in[2];
  const float* W2p = (const float*)d_in[3];
  const float* b2p = (const float*)d_in[4];
  const float* W1f = (const float*)d_in[5];
  const float* b1f = (const float*)d_in[6];
  const float* W2f = (const float*)d_in[7];
  const float* b2f = (const float*)d_in[8];
  const float* W3f = (const float*)d_in[9];
  const float* b3f = (const float*)d_in[10];
  const int* idx = (const int*)d_in[11];
  float* out = (float*)d_out;

  char* ws = (char*)d_ws;
  float* Txp = (float*)ws;                                   // 1 MB
  float* Ty = (float*)(ws + (1u << 20));                     // 1 MB
  unsigned short* W2s = (unsigned short*)(ws + (2u << 20));  // 512 KB

  hipLaunchKernelGGL(pre_kernel, dim3(1024), dim3(512), 0, stream,
                     W1p, b1p, W2p, b2p, W1f, b1f, W2f, idx, Txp, Ty, W2s);
  hipLaunchKernelGGL(main_kernel, dim3(64, 64), dim3(512), 0, stream,
                     Txp, Ty, W2s, b2f, W3f, b3f, out);
}

// Round 11
// 233.738 us; speedup vs baseline: 1.0694x; 1.0562x over previous
//
#include <hip/hip_runtime.h>
#include <stdint.h>

// ---------------------------------------------------------------------------
// NIVR: coord-MLP over 512x512 grid.
//   pre_kernel (1024 blocks): blocks 0..511: time branch inline + Txp/Ty
//     posenc tables (tvec folded into Txp); blocks 512..1023: W2f -> bf16
//     W2s (16x16x32 A-operand frags, R12 layout).
//   main: h1 = relu(Txp[x]+Ty[y]); layer2 via MFMA bf16 16x16x32 (swapped
//     operands => acc holds h2^T); fused layer3 epilogue. Out [3][N].
//
// R20: empirical closure of the structure space. R12 (16x16x32, 16 MFMA/step,
// 4x4 acc, B depth-1, A at-use, stagger+setprio, 2 blk/CU) = 154us beats all
// seven 32x32 restructures (R14-R19: 177-346us). Corrected accounting: A-DS
// was overcounted 8x in R18/R19 theory (1024 b128 reads/CU = 12k cyc); no
// pipe exceeds ~35% -- the 16-chain step structure's intrinsic latency
// hiding is what the 4-chain variants lack. R20 = R12 verbatim with its one
// quantified defect fixed: fill had 4-way bank-conflicted uint2 writes
// (6.4M conflict-cyc ~ 8us). New fill: thread (p, q=s&3, h=s>>2) covers 8
// consecutive k (full j-span of one frag q-slot) => one ds_write_b128 per
// k-step-pair; pattern = 8 bank-groups x 8 phases = b128 minimum (0 extra).
// Read side byte-identical. Pre = merged 2-kernel form (R6: lowest overhead).
// ---------------------------------------------------------------------------

typedef short bf16x8 __attribute__((ext_vector_type(8)));
typedef float f32x4 __attribute__((ext_vector_type(4)));

#define PI_F 3.14159265358979323846f
#define SIDE 512
#define NPIX (SIDE * SIDE)

__device__ __forceinline__ unsigned short f2bf(float f) {
  unsigned int u = __float_as_uint(f);
  u += 0x7fffu + ((u >> 16) & 1u);
  return (unsigned short)(u >> 16);
}

// ---------------------------------------------------------------------------
// pre: 1024 blocks x 512 threads.
//   b in [0,512)    : time branch (redundant per block) -> tvec;
//                     Txp[b][k] = tvec[k] + sum_l enc[l] W1f[l][k]
//                     Ty [b][k] =           sum_l enc[l] W1f[20+l][k]
//   b in [512,1024) : W2f -> bf16 frag-swizzled W2s (k-row = b-512),
//                     16x16x32 B-operand frags (R12-verified):
//                     W2s[ks*16384 + nt*512 + q*128 + ni*8 + j]
//                       = bf16(W2f[ks*32 + q*8 + j][nt*16 + ni])
// ---------------------------------------------------------------------------
__global__ void pre_kernel(const float* __restrict__ W1p, const float* __restrict__ b1p,
                           const float* __restrict__ W2p, const float* __restrict__ b2p,
                           const float* __restrict__ W1f, const float* __restrict__ b1f,
                           const float* __restrict__ W2f, const int* __restrict__ idx,
                           float* __restrict__ Txp, float* __restrict__ Ty,
                           unsigned short* __restrict__ W2s) {
  const int b = blockIdx.x;
  const int t = threadIdx.x;

  if (b >= 512) {
    const int k = b - 512, n = t;
    const int ks = k >> 5, q = (k >> 3) & 3, j = k & 7;
    const int nt = n >> 4, ni = n & 15;
    W2s[ks * 16384 + nt * 512 + q * 128 + ni * 8 + j] = f2bf(W2f[k * 512 + n]);
    return;
  }

  __shared__ float enc[20];
  __shared__ float r_s[32];
  __shared__ float h_s[256];
  __shared__ float phi_s[128];

  if (t < 10) {
    float u = (float)b / 512.0f;
    float ang = u * ldexpf(PI_F, t);
    enc[t] = sinf(ang);
    enc[10 + t] = cosf(ang);
  }
  if (t >= 32 && t < 48) {
    const int l = t - 32;
    float tt = (float)idx[0] / 300.0f;
    float ang = tt * ldexpf(PI_F, l);
    r_s[l] = sinf(ang);
    r_s[16 + l] = cosf(ang);
  }
  __syncthreads();
  if (t < 256) {
    float a = b1p[t];
#pragma unroll
    for (int i = 0; i < 32; ++i) a += r_s[i] * W1p[i * 256 + t];
    h_s[t] = fmaxf(a, 0.f);
  }
  __syncthreads();
  if (t < 128) {
    float a = b2p[t];
    for (int i = 0; i < 256; ++i) a += h_s[i] * W2p[i * 128 + t];
    phi_s[t] = a;
  }
  __syncthreads();
  {
    float tv = b1f[t];
    for (int p = 0; p < 128; ++p) tv += phi_s[p] * W1f[(40 + p) * 512 + t];
    float ax = tv, ay = 0.f;
#pragma unroll
    for (int l = 0; l < 20; ++l) {
      ax += enc[l] * W1f[l * 512 + t];
      ay += enc[l] * W1f[(20 + l) * 512 + t];
    }
    Txp[b * 512 + t] = ax;
    Ty[b * 512 + t] = ay;
  }
}

// ---------------------------------------------------------------------------
// Main fused kernel (R12 structure, verbatim K-loop/epilogue).
// Block = 512 thr (8 waves), BM=64 (8x8 patch), BN=512, K=512 in 16 steps
// of 32. Wave w owns N-slice [w*64, w*64+64).
// A tile 64KB resident in LDS (filled once); B via depth-1 register prefetch.
// Wave w walks K starting at step 2w (stagger; acc is order-independent).
// acc[mt][nt][r] = h2[pix=mt*16+lr][col=w*64+nt*16+q*4+r]
// ---------------------------------------------------------------------------
__global__ __launch_bounds__(512, 4) void main_kernel(
    const float* __restrict__ Txp, const float* __restrict__ Ty,
    const unsigned short* __restrict__ W2s, const float* __restrict__ b2f,
    const float* __restrict__ W3f, const float* __restrict__ b3f,
    float* __restrict__ out) {
  __shared__ __attribute__((aligned(16))) unsigned short Ab[16 * 2048];  // 64KB
  __shared__ float part[8][64][3];                                       // 6KB

  const int t = threadIdx.x;
  const int w = t >> 6;            // wave id 0..7  (N-slice)
  const int lane = t & 63;
  const int q = lane >> 4;
  const int lr = lane & 15;
  const int x0 = blockIdx.x * 8, y0 = blockIdx.y * 8;

  // K-loop phase offset per wave (SGPR): wave w starts at K-step 2w.
  const int kofs = __builtin_amdgcn_readfirstlane((w * 2) & 15);

  // B: wave w owns nt-slots w*4..w*4+3; frag (ks,nt) at +ks*16384 + nt*512;
  // lane reads at +lane*8 (16B, coalesced 1KB/wave).
  const unsigned short* bptr = W2s + (w * 4) * 512 + lane * 8;

  // ---- B pipeline: depth 1 (2 buffers). breg[ks&1] used at loop pos ks. ----
  bf16x8 breg[2][4];
#pragma unroll
  for (int nt = 0; nt < 4; ++nt)
    breg[0][nt] = *(const bf16x8*)(bptr + kofs * 16384 + nt * 512);

  // ---- A fill (once), conflict-minimal b128 form: thread (p = t>>3,
  // q = t&3, h = (t>>2)&1) covers pixel p, k = ks*32 + q*8 .. +7 for
  // ks = g*2+h (g = 0..7): 8 consecutive k = full j-span of frag slot q
  // => one ds_write_b128 at ks*2048 + (p>>4)*512 + q*128 + (p&15)*8.
  // Write pattern: 8 bank-groups x 8 phases = b128 minimum (0 extra
  // conflict cycles; old uint2 fill was 4-way conflicted, 6.4M cyc).
  // Read side byte-identical to R12.
  {
    const int p = t >> 3, s = t & 7;
    const int qf = s & 3, h = s >> 2;
    const int xi = x0 + (p >> 3), yi = y0 + (p & 7);
    const float* txp = Txp + xi * 512 + qf * 8;
    const float* typ = Ty + yi * 512 + qf * 8;
    const int abase = (p >> 4) * 512 + qf * 128 + (p & 15) * 8;
#pragma unroll
    for (int g = 0; g < 8; ++g) {
      const int ks = g * 2 + h;
      float4 a0 = *(const float4*)(txp + ks * 32);
      float4 a1 = *(const float4*)(txp + ks * 32 + 4);
      float4 b0 = *(const float4*)(typ + ks * 32);
      float4 b1 = *(const float4*)(typ + ks * 32 + 4);
      float v0 = fmaxf(a0.x + b0.x, 0.f), v1 = fmaxf(a0.y + b0.y, 0.f);
      float v2 = fmaxf(a0.z + b0.z, 0.f), v3 = fmaxf(a0.w + b0.w, 0.f);
      float v4 = fmaxf(a1.x + b1.x, 0.f), v5 = fmaxf(a1.y + b1.y, 0.f);
      float v6 = fmaxf(a1.z + b1.z, 0.f), v7 = fmaxf(a1.w + b1.w, 0.f);
      uint4 pk;
      asm("v_cvt_pk_bf16_f32 %0, %1, %2" : "=v"(pk.x) : "v"(v0), "v"(v1));
      asm("v_cvt_pk_bf16_f32 %0, %1, %2" : "=v"(pk.y) : "v"(v2), "v"(v3));
      asm("v_cvt_pk_bf16_f32 %0, %1, %2" : "=v"(pk.z) : "v"(v4), "v"(v5));
      asm("v_cvt_pk_bf16_f32 %0, %1, %2" : "=v"(pk.w) : "v"(v6), "v"(v7));
      *(uint4*)&Ab[ks * 2048 + abase] = pk;
    }
  }

  f32x4 acc[4][4];
#pragma unroll
  for (int i = 0; i < 4; ++i)
#pragma unroll
    for (int j2 = 0; j2 < 4; ++j2) acc[i][j2] = (f32x4){0.f, 0.f, 0.f, 0.f};

  __syncthreads();  // publishes A; the only barrier before the epilogue

  // ---- K-loop, fully unrolled, no barriers; wave-staggered start ----
#pragma unroll
  for (int ks = 0; ks < 16; ++ks) {
    const int kk = (ks + kofs) & 15;   // this wave's K-step this iteration
    // B loads for loop pos ks+1 (K-step kk+1), issued before this step's MFMAs
    if (ks + 1 < 16) {
      const int kn = (kk + 1) & 15;
#pragma unroll
      for (int nt = 0; nt < 4; ++nt)
        breg[(ks + 1) & 1][nt] =
            *(const bf16x8*)(bptr + kn * 16384 + nt * 512);
    }
    // A-frags for K-step kk: 4 ds_read_b128 sharing one vaddr (+imm offsets)
    const unsigned short* arow = &Ab[kk * 2048 + lane * 8];
    bf16x8 a0 = *(const bf16x8*)&arow[0 * 512];
    bf16x8 a1 = *(const bf16x8*)&arow[1 * 512];
    bf16x8 a2 = *(const bf16x8*)&arow[2 * 512];
    bf16x8 a3 = *(const bf16x8*)&arow[3 * 512];
    // MFMAs for K-step kk -- OPERANDS SWAPPED: D = W2slice^T x h1slice^T.
    __builtin_amdgcn_s_setprio(1);
#pragma unroll
    for (int nt = 0; nt < 4; ++nt) {
      acc[0][nt] = __builtin_amdgcn_mfma_f32_16x16x32_bf16(
          breg[ks & 1][nt], a0, acc[0][nt], 0, 0, 0);
      acc[1][nt] = __builtin_amdgcn_mfma_f32_16x16x32_bf16(
          breg[ks & 1][nt], a1, acc[1][nt], 0, 0, 0);
      acc[2][nt] = __builtin_amdgcn_mfma_f32_16x16x32_bf16(
          breg[ks & 1][nt], a2, acc[2][nt], 0, 0, 0);
      acc[3][nt] = __builtin_amdgcn_mfma_f32_16x16x32_bf16(
          breg[ks & 1][nt], a3, acc[3][nt], 0, 0, 0);
    }
    __builtin_amdgcn_s_setprio(0);
  }

  // ---- epilogue: h2 = relu(acc + b2f); rgb partial = h2 @ W3f.
  // Layer-3 k-dim (col) lives on (q,r) in-register; streamed per-nt to keep
  // peak register pressure ~96. Reduce over q via shfl_xor 16,32. ----
  {
    float p3[4][3];
#pragma unroll
    for (int mt = 0; mt < 4; ++mt) {
      p3[mt][0] = 0.f; p3[mt][1] = 0.f; p3[mt][2] = 0.f;
    }
#pragma unroll
    for (int nt = 0; nt < 4; ++nt) {
      const int k0 = w * 64 + nt * 16 + q * 4;
      float4 bv = *(const float4*)&b2f[k0];
      float bb[4] = {bv.x, bv.y, bv.z, bv.w};
      float4 u0 = *(const float4*)&W3f[k0 * 3 + 0];
      float4 u1 = *(const float4*)&W3f[k0 * 3 + 4];
      float4 u2 = *(const float4*)&W3f[k0 * 3 + 8];
      float wv[4][3];
      wv[0][0] = u0.x; wv[0][1] = u0.y; wv[0][2] = u0.z;
      wv[1][0] = u0.w; wv[1][1] = u1.x; wv[1][2] = u1.y;
      wv[2][0] = u1.z; wv[2][1] = u1.w; wv[2][2] = u2.x;
      wv[3][0] = u2.y; wv[3][1] = u2.z; wv[3][2] = u2.w;
#pragma unroll
      for (int mt = 0; mt < 4; ++mt)
#pragma unroll
        for (int r = 0; r < 4; ++r) {
          float h2 = fmaxf(acc[mt][nt][r] + bb[r], 0.f);
          p3[mt][0] += h2 * wv[r][0];
          p3[mt][1] += h2 * wv[r][1];
          p3[mt][2] += h2 * wv[r][2];
        }
    }
    // reduce partial over q (lanes l, l^16, l^32, l^48)
#pragma unroll
    for (int d = 16; d < 64; d <<= 1)
#pragma unroll
      for (int mt = 0; mt < 4; ++mt)
#pragma unroll
        for (int cc = 0; cc < 3; ++cc)
          p3[mt][cc] += __shfl_xor(p3[mt][cc], d, 64);
    if (q < 3) {
#pragma unroll
      for (int mt = 0; mt < 4; ++mt) part[w][mt * 16 + lr][q] = p3[mt][q];
    }
  }
  __syncthreads();
  if (t < 192) {
    const int c = t >> 6, mm = t & 63;
    float sum = b3f[c];
#pragma unroll
    for (int ww = 0; ww < 8; ++ww) sum += part[ww][mm][c];
    const int n = (x0 + (mm >> 3)) * 512 + (y0 + (mm & 7));
    out[c * NPIX + n] = sum;
  }
}

// ---------------------------------------------------------------------------
// Inputs: 0 coords (unused), 1 W1p, 2 b1p, 3 W2p, 4 b2p, 5 W1f, 6 b1f,
//         7 W2f, 8 b2f, 9 W3f, 10 b3f, 11 idx
// ---------------------------------------------------------------------------
extern "C" void kernel_launch(void* const* d_in, const int* in_sizes, int n_in,
                              void* d_out, int out_size, void* d_ws, size_t ws_size,
                              hipStream_t stream) {
  const float* W1p = (const float*)d_in[1];
  const float* b1p = (const float*)d_in[2];
  const float* W2p = (const float*)d_in[3];
  const float* b2p = (const float*)d_in[4];
  const float* W1f = (const float*)d_in[5];
  const float* b1f = (const float*)d_in[6];
  const float* W2f = (const float*)d_in[7];
  const float* b2f = (const float*)d_in[8];
  const float* W3f = (const float*)d_in[9];
  const float* b3f = (const float*)d_in[10];
  const int* idx = (const int*)d_in[11];
  float* out = (float*)d_out;

  char* ws = (char*)d_ws;
  float* Txp = (float*)ws;                                   // 1 MB
  float* Ty = (float*)(ws + (1u << 20));                     // 1 MB
  unsigned short* W2s = (unsigned short*)(ws + (2u << 20));  // 512 KB

  hipLaunchKernelGGL(pre_kernel, dim3(1024), dim3(512), 0, stream,
                     W1p, b1p, W2p, b2p, W1f, b1f, W2f, idx, Txp, Ty, W2s);
  hipLaunchKernelGGL(main_kernel, dim3(64, 64), dim3(512), 0, stream,
                     Txp, Ty, W2s, b2f, W3f, b3f, out);
}